// Round 17
// baseline (233.502 us; speedup 1.0000x reference)
//
#include <hip/hip_runtime.h>
#include <hip/hip_bf16.h>

#define BSg   32
#define NAg   128
#define NEg   16256
#define EMBg  64
#define H1g   256

typedef __attribute__((ext_vector_type(8))) short  short8;
typedef __attribute__((ext_vector_type(4))) float  f32x4;

__device__ __forceinline__ unsigned short f2bf16u(float x) {
    union { __hip_bfloat16 h; unsigned short u; } cv;
    cv.h = __float2bfloat16(x);
    return cv.u;
}
// hardware packed f32x2 -> bf16x2 (v_cvt_pk_bf16_f32)
__device__ __forceinline__ unsigned int pack2(float a, float b) {
    union { __hip_bfloat162 h; unsigned int u; } cv;
    cv.h = __float22bfloat162_rn(make_float2(a, b));
    return cv.u;
}

// ---- pack mlp1_w1 fp32 -> bf16 in MFMA-B-fragment layout [K/8][N][8] ----
__global__ void pack_weights(const float* __restrict__ w1, unsigned short* __restrict__ w1p)
{
    int i = blockIdx.x * 256 + threadIdx.x;
    if (i < 320 * 256) {
        int k = i >> 8, n = i & 255;
        w1p[(k >> 3) * (256 * 8) + n * 8 + (k & 7)] = f2bf16u(w1[i]);
    }
}

// ---- edge pipeline, BARRIER-FREE GEMM: block = (b, dst), 8 waves (512 thr).
// Key remap vs R9: wave (half,wq) computes its OWN 16-row strip (the edges it
// built, A-fragment blocks (ks, m=wq)) x ALL 256 cols, instead of 64 rows x 64
// cols. Since each wave reads only LDS it wrote itself, the build->GEMM
// __syncthreads() disappears entirely -- 8 independent wave pipelines, no
// correlated barrier drain (the ~20% dead time R3-R16 could not remove).
// B loads go 40->160/wave but all waves read the SAME 16KB W1 panel per ks
// (L1-resident); per-wave ds_reads drop 40->10. Per-wave 256-float partial
// column-sums land in the wave's own (dead) ks=0 LDS block; two cheap
// barriers at the end combine 8 partials and do the in-block W2 matvec.
__global__ __launch_bounds__(512, 4) void edge_kernel(
    const float* __restrict__ x0, const float* __restrict__ x_last,
    const float* __restrict__ edge_attr, const float* __restrict__ conv_w,
    const float* __restrict__ conv_b, const unsigned short* __restrict__ w1p,
    const float* __restrict__ b1, const float* __restrict__ w2f,
    const float* __restrict__ b2, float* __restrict__ agg)
{
    __shared__ unsigned short fragA[2][10 * 4 * 64 * 8];   // 2 x 40960 B = 81920 B exactly

    const int bd = blockIdx.x;           // b*128 + d   (no swizzle: R16 showed neutral)
    const int b  = bd >> 7, d = bd & 127;

    const int tid  = threadIdx.x;
    const int w8   = tid >> 6, lane = tid & 63;
    const int half = w8 >> 2, wq = w8 & 3;
    const int llo  = lane & 15, lhi = lane >> 4;      // k-chunk owner == lhi
    const bool padthread = (half == 1 && wq == 3 && lhi == 3);   // strip row 15 = edge 127

    // ---------- build A strip (this wave's 16 edges; lane-linear LDS writes) ----------
    {
        const int j  = wq * 16 + llo;            // edge-in-tile 0..63
        const int el = half * 64 + j;            // edge ordinal for this dst, 0..127
        int s = el + (el >= d ? 1 : 0);          // src node (skip d)
        if (s > 127) s = 127;                    // pad row (el==127): clamp, masked later
        int e = s * 127 + d - (s < d ? 1 : 0);   // global edge index (src-major layout)
        if (e > NEg - 1) e = NEg - 1;

        const float4* nfp = (const float4*)(x0        + (((size_t)b * NAg + s) << 5) + (lhi << 3));
        const float4* eap = (const float4*)(edge_attr + (((size_t)b * NEg + e) << 5) + (lhi << 3));
        float4 nf0 = nfp[0], nf1 = nfp[1];
        float4 ea0 = eap[0], ea1 = eap[1];

        #pragma unroll
        for (int o = 0; o < 8; ++o) {
            const float w0 = conv_w[2 * o], w1v = conv_w[2 * o + 1], cb = conv_b[o];
            float y0 = fmaxf(fmaf(w0, nf0.x, fmaf(w1v, ea0.x, cb)), 0.f);
            float y1 = fmaxf(fmaf(w0, nf0.y, fmaf(w1v, ea0.y, cb)), 0.f);
            float y2 = fmaxf(fmaf(w0, nf0.z, fmaf(w1v, ea0.z, cb)), 0.f);
            float y3 = fmaxf(fmaf(w0, nf0.w, fmaf(w1v, ea0.w, cb)), 0.f);
            float y4 = fmaxf(fmaf(w0, nf1.x, fmaf(w1v, ea1.x, cb)), 0.f);
            float y5 = fmaxf(fmaf(w0, nf1.y, fmaf(w1v, ea1.y, cb)), 0.f);
            float y6 = fmaxf(fmaf(w0, nf1.z, fmaf(w1v, ea1.z, cb)), 0.f);
            float y7 = fmaxf(fmaf(w0, nf1.w, fmaf(w1v, ea1.w, cb)), 0.f);
            uint4 pk;
            pk.x = pack2(y0, y1); pk.y = pack2(y2, y3);
            pk.z = pack2(y4, y5); pk.w = pack2(y6, y7);
            // block (ks=o, m=wq), slot low6 = lhi*16+llo = lane  (wave-local region)
            *(uint4*)&fragA[half][(((o * 4 + wq) * 64) + lane) * 8] = pk;
        }
        {
            const float4* lsp = (const float4*)(x_last + (((size_t)b * NAg + s) << 6) + (lhi << 4));
            float4 l0 = lsp[0], l1 = lsp[1], l2 = lsp[2], l3 = lsp[3];
            uint4 pa, pb;
            pa.x = pack2(l0.x, l0.y); pa.y = pack2(l0.z, l0.w);
            pa.z = pack2(l1.x, l1.y); pa.w = pack2(l1.z, l1.w);
            pb.x = pack2(l2.x, l2.y); pb.y = pack2(l2.z, l2.w);
            pb.z = pack2(l3.x, l3.y); pb.w = pack2(l3.z, l3.w);
            // k = 256 + lhi*16 + c : ks = 8+(lhi>>1), kchunk = (lhi&1)*2 (+1 for 2nd 8)
            const int ks8  = 8 + (lhi >> 1);
            const int slot = (ks8 * 4 + wq) * 64 + ((lhi & 1) * 2) * 16 + llo;
            *(uint4*)&fragA[half][slot * 8]        = pa;   // still block (ks8, wq): wave-local
            *(uint4*)&fragA[half][(slot + 16) * 8] = pb;
        }
    }
    // NO __syncthreads(): this wave reads only LDS it wrote (DS pipe in-order per wave)

    // ---------- GEMM1 strip: [16x320] @ [320x256]; wave owns rows wq*16..+15, all cols ----------
    f32x4 acc[16];
    #pragma unroll
    for (int n = 0; n < 16; ++n)
        acc[n] = (f32x4){0.f, 0.f, 0.f, 0.f};

    #pragma unroll
    for (int ks = 0; ks < 10; ++ks) {
        short8 af = *(const short8*)&fragA[half][((ks * 4 + wq) * 64 + lane) * 8];
        #pragma unroll
        for (int n = 0; n < 16; ++n) {
            short8 bf = *(const short8*)&w1p[((ks * 4 + lhi) * H1g + n * 16 + llo) * 8];
            acc[n] = __builtin_amdgcn_mfma_f32_16x16x32_bf16(af, bf, acc[n], 0, 0, 0);
        }
    }

    // ---------- relu(+bias), column-sum over this wave's 16 rows (mask pad el==127) ----------
    // Partials go into the wave's OWN ks=0 fragment block (done reading it) -> no barrier.
    {
        float* myh1 = (float*)&fragA[half][(wq * 64) * 8];   // 256 floats, wave-owned
        #pragma unroll
        for (int n = 0; n < 16; ++n) {
            const float bias = b1[n * 16 + llo];
            float p = 0.f;
            #pragma unroll
            for (int i = 0; i < 4; ++i) {
                float v = fmaxf(acc[n][i] + bias, 0.f);
                if (!(padthread && i == 3)) p += v;
            }
            p += __shfl_xor(p, 16, 64);
            p += __shfl_xor(p, 32, 64);
            if (lhi == 0) myh1[n * 16 + llo] = p;
        }
    }
    __syncthreads();   // all 8 partial vectors visible

    // ---------- matvec: agg[b,d,:] = (sum of 8 partials) @ W2 + 127*b2 ----------
    const float* F0 = (const float*)&fragA[0][0];   // partial (h=0,wq) at F0[wq*256+k]
    const float* F1 = (const float*)&fragA[1][0];   // partial (h=1,wq) at F1[wq*256+k]
    float* redS = (float*)&fragA[0][0] + 1024;      // ks=1 region of fragA[0]: unused now

    {
        const int c = tid & 63, kq = w8;            // kq = wave id: k-range kq*32..+31
        float p = 0.f;
        #pragma unroll 4
        for (int k0 = 0; k0 < 32; ++k0) {
            int k = kq * 32 + k0;
            float h = F0[k] + F0[256 + k] + F0[512 + k] + F0[768 + k]
                    + F1[k] + F1[256 + k] + F1[512 + k] + F1[768 + k];
            p = fmaf(h, w2f[k * 64 + c], p);
        }
        redS[kq * 64 + c] = p;
    }
    __syncthreads();
    if (tid < 64) {
        float v = redS[tid]       + redS[64 + tid]  + redS[128 + tid] + redS[192 + tid]
                + redS[256 + tid] + redS[320 + tid] + redS[384 + tid] + redS[448 + tid]
                + 127.f * b2[tid];
        agg[((size_t)bd << 6) + tid] = v;
    }
}

// ---- node pipeline (R9's known-good 8-row version) ----
__global__ __launch_bounds__(256) void node_kernel(
    const float* __restrict__ x0, const float* __restrict__ x_last,
    const float* __restrict__ agg, const float* __restrict__ w1,
    const float* __restrict__ b1, const float* __restrict__ w2,
    const float* __restrict__ b2, float* __restrict__ out)
{
    __shared__ float lf[8][160];
    __shared__ float h2s[8][257];
    const int tid = threadIdx.x;
    const int r0  = blockIdx.x * 8;   // global node-row = b*128 + a

    for (int idx = tid; idx < 8 * 160; idx += 256) {
        int r = idx / 160, c = idx % 160;
        int gr = r0 + r;
        int bb = gr >> 7, a = gr & 127;
        float v;
        if (c < 32)      v = x0[(((size_t)bb * NAg + a) << 5) + c];
        else if (c < 96) v = x_last[(((size_t)bb * NAg + a) << 6) + (c - 32)];
        else             v = agg[((size_t)gr << 6) + (c - 96)];
        lf[r][c] = v;
    }
    __syncthreads();

    {   // layer 1: thread == output column (w1[k*256+c] coalesced)
        const int c = tid;
        float acc[8];
        const float bb = b1[c];
        #pragma unroll
        for (int r = 0; r < 8; ++r) acc[r] = bb;
        #pragma unroll 4
        for (int k = 0; k < 160; ++k) {
            float wv = w1[k * 256 + c];
            #pragma unroll
            for (int r = 0; r < 8; ++r) acc[r] = fmaf(lf[r][k], wv, acc[r]);
        }
        #pragma unroll
        for (int r = 0; r < 8; ++r) h2s[r][c] = fmaxf(acc[r], 0.f);
    }
    __syncthreads();

    {   // layer 2: thread -> (n = tid&63, 2 rows) (w2[k*64+n] coalesced)
        const int n = tid & 63, rq = tid >> 6;
        float acc[2];
        const float bb = b2[n];
        #pragma unroll
        for (int j = 0; j < 2; ++j) acc[j] = bb;
        #pragma unroll 4
        for (int k = 0; k < 256; ++k) {
            float wv = w2[k * 64 + n];
            #pragma unroll
            for (int j = 0; j < 2; ++j) acc[j] = fmaf(h2s[rq * 2 + j][k], wv, acc[j]);
        }
        #pragma unroll
        for (int j = 0; j < 2; ++j)
            out[((size_t)(r0 + rq * 2 + j) << 6) + n] = acc[j];
    }
}

extern "C" void kernel_launch(void* const* d_in, const int* in_sizes, int n_in,
                              void* d_out, int out_size, void* d_ws, size_t ws_size,
                              hipStream_t stream)
{
    const float* x0       = (const float*)d_in[0];
    const float* x_last   = (const float*)d_in[1];
    const float* edge_attr= (const float*)d_in[2];
    const float* conv_w   = (const float*)d_in[3];
    const float* conv_b   = (const float*)d_in[4];
    const float* mlp1_w1  = (const float*)d_in[5];
    const float* mlp1_b1  = (const float*)d_in[6];
    const float* mlp1_w2  = (const float*)d_in[7];
    const float* mlp1_b2  = (const float*)d_in[8];
    const float* mlp2_w1  = (const float*)d_in[9];
    const float* mlp2_b1  = (const float*)d_in[10];
    const float* mlp2_w2  = (const float*)d_in[11];
    const float* mlp2_b2  = (const float*)d_in[12];

    char* ws = (char*)d_ws;
    unsigned short* w1p = (unsigned short*)ws;                // 160 KB @ 0
    float* agg          = (float*)(ws + (1 << 20));           // 1 MB, fully written

    pack_weights<<<320, 256, 0, stream>>>(mlp1_w1, w1p);
    edge_kernel<<<BSg * NAg, 512, 0, stream>>>(x0, x_last, edge_attr, conv_w, conv_b,
                                               w1p, mlp1_b1, mlp1_w2, mlp1_b2, agg);
    node_kernel<<<(BSg * NAg) / 8, 256, 0, stream>>>(x0, x_last, agg, mlp2_w1, mlp2_b1,
                                                     mlp2_w2, mlp2_b2, (float*)d_out);
}